// Round 2
// baseline (499.234 us; speedup 1.0000x reference)
//
#include <hip/hip_runtime.h>
#include <hip/hip_bf16.h>

#define D 1024
#define BLOCK 256
#define GRID 2048   // 8 blocks/CU nominal; each wave grid-strides over rows

__global__ __launch_bounds__(BLOCK) void CosineSimilarity_76785425318088_kernel(
    const float* __restrict__ premise,
    const float* __restrict__ hypothesis,
    float* __restrict__ out,
    int n_rows) {
    const int lane = threadIdx.x & 63;
    const int wave_global = (blockIdx.x * BLOCK + threadIdx.x) >> 6;   // global wave id
    const int n_waves = (GRID * BLOCK) >> 6;                           // total waves
    const float eps = 1e-12f;

    // Each wave processes 2 rows per iteration (n_rows is even): doubles the
    // number of loads in flight (16 x 16B/lane) and amortizes the shuffle tail.
    for (int row = wave_global * 2; row < n_rows; row += n_waves * 2) {
        const float4* __restrict__ p0 = reinterpret_cast<const float4*>(premise    + (size_t)row * D);
        const float4* __restrict__ h0 = reinterpret_cast<const float4*>(hypothesis + (size_t)row * D);
        const float4* __restrict__ p1 = reinterpret_cast<const float4*>(premise    + (size_t)(row + 1) * D);
        const float4* __restrict__ h1 = reinterpret_cast<const float4*>(hypothesis + (size_t)(row + 1) * D);

        float d0 = 0.f, pp0 = 0.f, hh0 = 0.f;
        float d1 = 0.f, pp1 = 0.f, hh1 = 0.f;

        #pragma unroll
        for (int j = 0; j < D / 4 / 64; ++j) {   // 4 iterations, fully unrolled
            float4 a0 = p0[j * 64 + lane];
            float4 b0 = h0[j * 64 + lane];
            float4 a1 = p1[j * 64 + lane];
            float4 b1 = h1[j * 64 + lane];
            d0  = fmaf(a0.x, b0.x, d0);  d0  = fmaf(a0.y, b0.y, d0);
            d0  = fmaf(a0.z, b0.z, d0);  d0  = fmaf(a0.w, b0.w, d0);
            pp0 = fmaf(a0.x, a0.x, pp0); pp0 = fmaf(a0.y, a0.y, pp0);
            pp0 = fmaf(a0.z, a0.z, pp0); pp0 = fmaf(a0.w, a0.w, pp0);
            hh0 = fmaf(b0.x, b0.x, hh0); hh0 = fmaf(b0.y, b0.y, hh0);
            hh0 = fmaf(b0.z, b0.z, hh0); hh0 = fmaf(b0.w, b0.w, hh0);
            d1  = fmaf(a1.x, b1.x, d1);  d1  = fmaf(a1.y, b1.y, d1);
            d1  = fmaf(a1.z, b1.z, d1);  d1  = fmaf(a1.w, b1.w, d1);
            pp1 = fmaf(a1.x, a1.x, pp1); pp1 = fmaf(a1.y, a1.y, pp1);
            pp1 = fmaf(a1.z, a1.z, pp1); pp1 = fmaf(a1.w, a1.w, pp1);
            hh1 = fmaf(b1.x, b1.x, hh1); hh1 = fmaf(b1.y, b1.y, hh1);
            hh1 = fmaf(b1.z, b1.z, hh1); hh1 = fmaf(b1.w, b1.w, hh1);
        }

        // Wave-64 butterfly reduction (wavefront = 64 on CDNA).
        #pragma unroll
        for (int off = 32; off > 0; off >>= 1) {
            d0  += __shfl_down(d0,  off, 64);
            pp0 += __shfl_down(pp0, off, 64);
            hh0 += __shfl_down(hh0, off, 64);
            d1  += __shfl_down(d1,  off, 64);
            pp1 += __shfl_down(pp1, off, 64);
            hh1 += __shfl_down(hh1, off, 64);
        }

        if (lane == 0) {
            out[row]     = d0 / (fmaxf(sqrtf(pp0), eps) * fmaxf(sqrtf(hh0), eps));
            out[row + 1] = d1 / (fmaxf(sqrtf(pp1), eps) * fmaxf(sqrtf(hh1), eps));
        }
    }
}

extern "C" void kernel_launch(void* const* d_in, const int* in_sizes, int n_in,
                              void* d_out, int out_size, void* d_ws, size_t ws_size,
                              hipStream_t stream) {
    const float* premise    = (const float*)d_in[0];
    const float* hypothesis = (const float*)d_in[1];
    float* out = (float*)d_out;
    const int n_rows = out_size;  // 65536

    CosineSimilarity_76785425318088_kernel<<<GRID, BLOCK, 0, stream>>>(
        premise, hypothesis, out, n_rows);
}